// Round 6
// baseline (231.324 us; speedup 1.0000x reference)
//
#include <hip/hip_runtime.h>
#include <hip/hip_bf16.h>

// KANLayer: out = x @ Wb^T + silu(x) @ sum_g(Ws)^T
// One packed bf16 GEMM, K=2048: A'=[x|silu(x)], W'=[Wb|sum_g Ws], out=A'@W'^T.
// R6: split-K x2 -> 1024 blocks = 4/CU at UNCHANGED 16 MFMA/wave per barrier
//     (R3 showed blocks alone don't help if per-barrier compute halves; m97's
//     874 TF config = 3 blocks/CU x 16 MFMA). R2's simple 2-barrier loop
//     (beats all my pipelining attempts) + slot-major conflict-free LDS (R4).
//     Epilogue: HW fp32 atomicAdd onto memset-zeroed C.

#define BATCH 8192
#define IN_F 1024
#define OUT_F 1024
#define KP 2048

typedef unsigned short ushort_t;
typedef __attribute__((ext_vector_type(8))) short short8;
typedef __attribute__((ext_vector_type(4))) float f32x4;

__device__ __forceinline__ ushort_t f2bf(float f) {
  union { float f; unsigned int u; } v;
  v.f = f;
  unsigned int u = v.u;
  u += 0x7fffu + ((u >> 16) & 1u);  // RNE
  return (ushort_t)(u >> 16);
}

__device__ __forceinline__ void async16(const ushort_t* g, ushort_t* l) {
  __builtin_amdgcn_global_load_lds(
      (const __attribute__((address_space(1))) void*)g,
      (__attribute__((address_space(3))) void*)l, 16, 0, 0);
}

// ---------------- merged prep (unchanged: ~traffic floor) -----------
#define PREP_A_BLOCKS 4096
#define PREP_S_BLOCKS 1024
#define PREP_B_BLOCKS 1024
#define PREP_BLOCKS (PREP_A_BLOCKS + PREP_S_BLOCKS + PREP_B_BLOCKS)

__global__ __launch_bounds__(256) void prep_all(
    const float* __restrict__ x, const float* __restrict__ Wb,
    const float* __restrict__ Ws, ushort_t* __restrict__ Apack,
    ushort_t* __restrict__ Wpack) {
  const int blk = blockIdx.x;
  const int t = threadIdx.x;

  if (blk < PREP_A_BLOCKS) {
    const int idx = blk * 256 + t;
    const int b = idx >> 7;
    const int i = (idx & 127) << 3;
    const float4 x0 = *(const float4*)(x + ((size_t)b << 10) + i);
    const float4 x1 = *(const float4*)(x + ((size_t)b << 10) + i + 4);
    float xv[8] = {x0.x, x0.y, x0.z, x0.w, x1.x, x1.y, x1.z, x1.w};
    ushort_t vb[8], vs[8];
#pragma unroll
    for (int j = 0; j < 8; ++j) {
      vb[j] = f2bf(xv[j]);
      vs[j] = f2bf(xv[j] / (1.0f + __expf(-xv[j])));
    }
    ushort_t* row = Apack + ((size_t)b << 11);
    *(short8*)(row + i) = *(short8*)vb;
    *(short8*)(row + IN_F + i) = *(short8*)vs;
  } else if (blk < PREP_A_BLOCKS + PREP_S_BLOCKS) {
    const int idx = (blk - PREP_A_BLOCKS) * 256 + t;
    const int o = idx >> 8;
    const int i0 = (idx & 255) << 2;
    ushort_t vs[4];
#pragma unroll
    for (int j = 0; j < 4; ++j) {
      const float4* p = (const float4*)(Ws + ((((size_t)o << 10) + i0 + j) << 3));
      const float4 a = p[0];
      const float4 b = p[1];
      vs[j] = f2bf(((a.x + a.y) + (a.z + a.w)) + ((b.x + b.y) + (b.z + b.w)));
    }
    *(ushort4*)(Wpack + ((size_t)o << 11) + IN_F + i0) = *(ushort4*)vs;
  } else {
    const int idx = (blk - PREP_A_BLOCKS - PREP_S_BLOCKS) * 256 + t;
    const int o = idx >> 8;
    const int c = (idx & 255) << 2;
    const float4 w = *(const float4*)(Wb + ((size_t)o << 10) + c);
    ushort4 v;
    v.x = f2bf(w.x); v.y = f2bf(w.y); v.z = f2bf(w.z); v.w = f2bf(w.w);
    *(ushort4*)(Wpack + ((size_t)o << 11) + c) = v;
  }
}

// ---------------- GEMM (split-K x2) ----------------
// C[M][N] += A[M][kz..kz+1024) @ W[N][kz..kz+1024)^T per K-half.
// 128x128 tile, BK=32, 256 thr = 4 waves, wave tile 64x64 (4x4 16x16x32).
// Grid (8, 64, 2) = 1024 blocks = 4/CU. Slot-major LDS (conflict-free).
__global__ __launch_bounds__(256) void gemm_packed(
    const ushort_t* __restrict__ A,  // [BATCH][KP]
    const ushort_t* __restrict__ W,  // [OUT_F][KP]
    float* __restrict__ C) {         // [BATCH][OUT_F], pre-zeroed
  __shared__ ushort_t As[4096];  // 8 KB: [kslot 0..3][row 0..127][8 elems]
  __shared__ ushort_t Bs[4096];

  const int t = threadIdx.x;
  const int flat = blockIdx.y * 8 + blockIdx.x;  // z-independent swizzle
  const int xcd = flat & 7;
  const int local = flat >> 3;           // 0..63
  const int nt = local >> 3;             // N-tile 0..7
  const int mt = xcd * 8 + (local & 7);  // M-tile 0..63 (XCD-local A slab)
  const int kbase = blockIdx.z << 10;    // 0 or 1024

  const int lane = t & 63;
  const int wave = t >> 6;
  const int wr = wave >> 1;
  const int wc = wave & 1;

  // staging: thread t covers (row=t&127, kslot=t>>7); 2 rounds fill 4 kslots
  const int srow = t & 127;
  const int sslot = t >> 7;
  const ushort_t* a_g = A + ((size_t)(mt * 128 + srow)) * KP + kbase + sslot * 8;
  const ushort_t* b_g = W + ((size_t)(nt * 128 + srow)) * KP + kbase + sslot * 8;
  const int t8 = t * 8;

  f32x4 acc[4][4];
#pragma unroll
  for (int mi = 0; mi < 4; ++mi)
#pragma unroll
    for (int ni = 0; ni < 4; ++ni) acc[mi][ni] = (f32x4){0.f, 0.f, 0.f, 0.f};

  const int arow = wr * 64 + (lane & 15);
  const int brow = wc * 64 + (lane & 15);
  const int rk = (lane >> 4) * 1024;  // kslot base (elems)

  for (int k0 = 0; k0 < 1024; k0 += 32) {
    __syncthreads();  // previous iter's reads done before overwrite
    async16(a_g + k0, As + t8);
    async16(a_g + k0 + 16, As + 2048 + t8);
    async16(b_g + k0, Bs + t8);
    async16(b_g + k0 + 16, Bs + 2048 + t8);
    __syncthreads();  // vmcnt(0) drain -> LDS ready

    const ushort_t* ab = As + rk;
    const ushort_t* bb = Bs + rk;
    short8 af[4], bfr[4];
#pragma unroll
    for (int mi = 0; mi < 4; ++mi)
      af[mi] = *(const short8*)(ab + (arow + mi * 16) * 8);
#pragma unroll
    for (int ni = 0; ni < 4; ++ni)
      bfr[ni] = *(const short8*)(bb + (brow + ni * 16) * 8);

#pragma unroll
    for (int mi = 0; mi < 4; ++mi)
#pragma unroll
      for (int ni = 0; ni < 4; ++ni)
        acc[mi][ni] = __builtin_amdgcn_mfma_f32_16x16x32_bf16(af[mi], bfr[ni], acc[mi][ni], 0, 0, 0);
  }

  // epilogue: HW fp32 atomic add (exactly 2 contributions per element)
  const int col0 = nt * 128 + wc * 64 + (lane & 15);
  const int row0 = mt * 128 + wr * 64 + ((lane >> 4) << 2);
#pragma unroll
  for (int mi = 0; mi < 4; ++mi)
#pragma unroll
    for (int ni = 0; ni < 4; ++ni) {
      float* cp = C + (size_t)(row0 + mi * 16) * OUT_F + col0 + ni * 16;
#pragma unroll
      for (int r = 0; r < 4; ++r) unsafeAtomicAdd(cp + (size_t)r * OUT_F, acc[mi][ni][r]);
    }
}

extern "C" void kernel_launch(void* const* d_in, const int* in_sizes, int n_in,
                              void* d_out, int out_size, void* d_ws, size_t ws_size,
                              hipStream_t stream) {
  const float* x = (const float*)d_in[0];
  const float* wb = (const float*)d_in[1];
  const float* ws = (const float*)d_in[2];
  float* out = (float*)d_out;

  ushort_t* Apack = (ushort_t*)d_ws;                                    // 33.5 MB
  ushort_t* Wpack = (ushort_t*)((char*)d_ws + (size_t)BATCH * KP * 2);  // +4 MB

  hipMemsetAsync(out, 0, (size_t)BATCH * OUT_F * sizeof(float), stream);
  prep_all<<<PREP_BLOCKS, 256, 0, stream>>>(x, wb, ws, Apack, Wpack);
  gemm_packed<<<dim3(OUT_F / 128, BATCH / 128, 2), 256, 0, stream>>>(Apack, Wpack, out);
}

// Round 7
// 187.598 us; speedup vs baseline: 1.2331x; 1.2331x over previous
//
#include <hip/hip_runtime.h>
#include <hip/hip_bf16.h>

// KANLayer: out = x @ Wb^T + silu(x) @ sum_g(Ws)^T
// One packed bf16 GEMM, K=2048: A'=[x|silu(x)], W'=[Wb|sum_g Ws], out=A'@W'^T.
// R7: 512-thread blocks (8 waves) on 128x128 tile, BK=64.
//     -> 16 waves/CU (R2 had 8) at UNCHANGED staging-bytes/FLOP,
//     -> half the barriers (32 iters vs 64), drain amortized over 2x compute.
//     Keep: R2's simple 2-barrier loop (beat all explicit pipelining),
//     slot-major conflict-free LDS (R4: conflicts 0), XCD swizzle (R2: fetch 1x).

#define BATCH 8192
#define IN_F 1024
#define OUT_F 1024
#define KP 2048

typedef unsigned short ushort_t;
typedef __attribute__((ext_vector_type(8))) short short8;
typedef __attribute__((ext_vector_type(4))) float f32x4;

__device__ __forceinline__ ushort_t f2bf(float f) {
  union { float f; unsigned int u; } v;
  v.f = f;
  unsigned int u = v.u;
  u += 0x7fffu + ((u >> 16) & 1u);  // RNE
  return (ushort_t)(u >> 16);
}

__device__ __forceinline__ void async16(const ushort_t* g, ushort_t* l) {
  __builtin_amdgcn_global_load_lds(
      (const __attribute__((address_space(1))) void*)g,
      (__attribute__((address_space(3))) void*)l, 16, 0, 0);
}

// ---------------- merged prep (unchanged: ~traffic floor) -----------
#define PREP_A_BLOCKS 4096
#define PREP_S_BLOCKS 1024
#define PREP_B_BLOCKS 1024
#define PREP_BLOCKS (PREP_A_BLOCKS + PREP_S_BLOCKS + PREP_B_BLOCKS)

__global__ __launch_bounds__(256) void prep_all(
    const float* __restrict__ x, const float* __restrict__ Wb,
    const float* __restrict__ Ws, ushort_t* __restrict__ Apack,
    ushort_t* __restrict__ Wpack) {
  const int blk = blockIdx.x;
  const int t = threadIdx.x;

  if (blk < PREP_A_BLOCKS) {
    const int idx = blk * 256 + t;
    const int b = idx >> 7;
    const int i = (idx & 127) << 3;
    const float4 x0 = *(const float4*)(x + ((size_t)b << 10) + i);
    const float4 x1 = *(const float4*)(x + ((size_t)b << 10) + i + 4);
    float xv[8] = {x0.x, x0.y, x0.z, x0.w, x1.x, x1.y, x1.z, x1.w};
    ushort_t vb[8], vs[8];
#pragma unroll
    for (int j = 0; j < 8; ++j) {
      vb[j] = f2bf(xv[j]);
      vs[j] = f2bf(xv[j] / (1.0f + __expf(-xv[j])));
    }
    ushort_t* row = Apack + ((size_t)b << 11);
    *(short8*)(row + i) = *(short8*)vb;
    *(short8*)(row + IN_F + i) = *(short8*)vs;
  } else if (blk < PREP_A_BLOCKS + PREP_S_BLOCKS) {
    const int idx = (blk - PREP_A_BLOCKS) * 256 + t;
    const int o = idx >> 8;
    const int i0 = (idx & 255) << 2;
    ushort_t vs[4];
#pragma unroll
    for (int j = 0; j < 4; ++j) {
      const float4* p = (const float4*)(Ws + ((((size_t)o << 10) + i0 + j) << 3));
      const float4 a = p[0];
      const float4 b = p[1];
      vs[j] = f2bf(((a.x + a.y) + (a.z + a.w)) + ((b.x + b.y) + (b.z + b.w)));
    }
    *(ushort4*)(Wpack + ((size_t)o << 11) + IN_F + i0) = *(ushort4*)vs;
  } else {
    const int idx = (blk - PREP_A_BLOCKS - PREP_S_BLOCKS) * 256 + t;
    const int o = idx >> 8;
    const int c = (idx & 255) << 2;
    const float4 w = *(const float4*)(Wb + ((size_t)o << 10) + c);
    ushort4 v;
    v.x = f2bf(w.x); v.y = f2bf(w.y); v.z = f2bf(w.z); v.w = f2bf(w.w);
    *(ushort4*)(Wpack + ((size_t)o << 11) + c) = v;
  }
}

// ---------------- GEMM ----------------
// C[M][N] = A[M][K] @ W[N][K]^T. 128x128 tile, BK=64, 512 thr = 8 waves,
// wave tile 32x64 (2x4 frags of 16x16x32, 2 K-steps -> 16 MFMA/wave/iter).
// Grid (8,64) = 512 blocks = 2/CU = 16 waves/CU (4/SIMD).
// Slot-major LDS: [kslot 0..7][row 0..127][8 elems=16B] per matrix (16 KB).
// Frag reads: 16 lanes stride 16B -> 2 lanes/bank -> conflict-free (R4-verified).
__global__ __launch_bounds__(512) void gemm_packed(
    const ushort_t* __restrict__ A,  // [BATCH][KP]
    const ushort_t* __restrict__ W,  // [OUT_F][KP]
    float* __restrict__ C) {         // [BATCH][OUT_F]
  __shared__ ushort_t As[8192];  // 16 KB
  __shared__ ushort_t Bs[8192];  // 16 KB

  const int t = threadIdx.x;
  const int flat = blockIdx.y * 8 + blockIdx.x;
  const int xcd = flat & 7;
  const int local = flat >> 3;           // 0..63
  const int nt = local >> 3;             // N-tile 0..7
  const int mt = xcd * 8 + (local & 7);  // M-tile 0..63 (XCD-local A slab)

  const int lane = t & 63;
  const int wave = t >> 6;   // 0..7
  const int wr = wave >> 1;  // 0..3 -> M offset wr*32
  const int wc = wave & 1;   // 0..1 -> N offset wc*64

  // staging: thread t covers (row = t&127, kslot = t>>7); round r adds 4 kslots
  const int srow = t & 127;
  const int sslot = t >> 7;  // 0..3
  const ushort_t* a_g = A + ((size_t)(mt * 128 + srow)) * KP + sslot * 8;
  const ushort_t* b_g = W + ((size_t)(nt * 128 + srow)) * KP + sslot * 8;
  ushort_t* as_d0 = As + t * 8;         // kslots 0..3
  ushort_t* as_d1 = As + 4096 + t * 8;  // kslots 4..7
  ushort_t* bs_d0 = Bs + t * 8;
  ushort_t* bs_d1 = Bs + 4096 + t * 8;

  f32x4 acc[2][4];
#pragma unroll
  for (int mi = 0; mi < 2; ++mi)
#pragma unroll
    for (int ni = 0; ni < 4; ++ni) acc[mi][ni] = (f32x4){0.f, 0.f, 0.f, 0.f};

  const int arow = wr * 32 + (lane & 15);
  const int brow = wc * 64 + (lane & 15);
  const int rk = (lane >> 4) * 1024;  // kslot-group base within a K-step

  for (int k0 = 0; k0 < KP; k0 += 64) {
    __syncthreads();  // previous iter's frag reads done before overwrite
    async16(a_g + k0, as_d0);
    async16(a_g + k0 + 32, as_d1);
    async16(b_g + k0, bs_d0);
    async16(b_g + k0 + 32, bs_d1);
    __syncthreads();  // drain -> LDS ready

#pragma unroll
    for (int s = 0; s < 2; ++s) {
      const ushort_t* ab = As + s * 4096 + rk;
      const ushort_t* bb = Bs + s * 4096 + rk;
      short8 af[2], bfr[4];
#pragma unroll
      for (int mi = 0; mi < 2; ++mi)
        af[mi] = *(const short8*)(ab + (arow + mi * 16) * 8);
#pragma unroll
      for (int ni = 0; ni < 4; ++ni)
        bfr[ni] = *(const short8*)(bb + (brow + ni * 16) * 8);

#pragma unroll
      for (int mi = 0; mi < 2; ++mi)
#pragma unroll
        for (int ni = 0; ni < 4; ++ni)
          acc[mi][ni] = __builtin_amdgcn_mfma_f32_16x16x32_bf16(af[mi], bfr[ni], acc[mi][ni], 0, 0, 0);
    }
  }

  const int col0 = nt * 128 + wc * 64 + (lane & 15);
  const int row0 = mt * 128 + wr * 32 + ((lane >> 4) << 2);
#pragma unroll
  for (int mi = 0; mi < 2; ++mi)
#pragma unroll
    for (int ni = 0; ni < 4; ++ni) {
      float* cp = C + (size_t)(row0 + mi * 16) * OUT_F + col0 + ni * 16;
#pragma unroll
      for (int r = 0; r < 4; ++r) cp[(size_t)r * OUT_F] = acc[mi][ni][r];
    }
}

extern "C" void kernel_launch(void* const* d_in, const int* in_sizes, int n_in,
                              void* d_out, int out_size, void* d_ws, size_t ws_size,
                              hipStream_t stream) {
  const float* x = (const float*)d_in[0];
  const float* wb = (const float*)d_in[1];
  const float* ws = (const float*)d_in[2];
  float* out = (float*)d_out;

  ushort_t* Apack = (ushort_t*)d_ws;                                    // 33.5 MB
  ushort_t* Wpack = (ushort_t*)((char*)d_ws + (size_t)BATCH * KP * 2);  // +4 MB

  prep_all<<<PREP_BLOCKS, 256, 0, stream>>>(x, wb, ws, Apack, Wpack);
  gemm_packed<<<dim3(OUT_F / 128, BATCH / 128), 512, 0, stream>>>(Apack, Wpack, out);
}

// Round 8
// 154.566 us; speedup vs baseline: 1.4966x; 1.2137x over previous
//
#include <hip/hip_runtime.h>
#include <hip/hip_bf16.h>

// KANLayer: out = x @ Wb^T + silu(x) @ sum_g(Ws)^T
// One packed bf16 GEMM, K=2048: A'=[x|silu(x)], W'=[Wb|sum_g Ws], out=A'@W'^T.
// R8: register-staged K-loop (global->VGPR->ds_write), decoupling:
//     - coalesced global loads (t>>2 pattern, 64B segments — the R2/R6 fast class;
//       R4/R5/R7's slot-major global_load_lds pattern was 16B/lane stride-4KB = slow class)
//     - slot-major + XOR-swizzled LDS (conflict-free b128 frag reads)
//     - real prefetch: tile k+1 loads issue at window top, consumed by ds_write
//       AFTER the MFMA phase; double-buffered LDS -> ONE barrier/window with
//       vmcnt already drained (kills R2's ~1000cyc/iter barrier drain).

#define BATCH 8192
#define IN_F 1024
#define OUT_F 1024
#define KP 2048

typedef unsigned short ushort_t;
typedef __attribute__((ext_vector_type(8))) short short8;
typedef __attribute__((ext_vector_type(4))) float f32x4;

__device__ __forceinline__ ushort_t f2bf(float f) {
  union { float f; unsigned int u; } v;
  v.f = f;
  unsigned int u = v.u;
  u += 0x7fffu + ((u >> 16) & 1u);  // RNE
  return (ushort_t)(u >> 16);
}

// ---------------- merged prep (unchanged: ~traffic floor) -----------
#define PREP_A_BLOCKS 4096
#define PREP_S_BLOCKS 1024
#define PREP_B_BLOCKS 1024
#define PREP_BLOCKS (PREP_A_BLOCKS + PREP_S_BLOCKS + PREP_B_BLOCKS)

__global__ __launch_bounds__(256) void prep_all(
    const float* __restrict__ x, const float* __restrict__ Wb,
    const float* __restrict__ Ws, ushort_t* __restrict__ Apack,
    ushort_t* __restrict__ Wpack) {
  const int blk = blockIdx.x;
  const int t = threadIdx.x;

  if (blk < PREP_A_BLOCKS) {
    const int idx = blk * 256 + t;
    const int b = idx >> 7;
    const int i = (idx & 127) << 3;
    const float4 x0 = *(const float4*)(x + ((size_t)b << 10) + i);
    const float4 x1 = *(const float4*)(x + ((size_t)b << 10) + i + 4);
    float xv[8] = {x0.x, x0.y, x0.z, x0.w, x1.x, x1.y, x1.z, x1.w};
    ushort_t vb[8], vs[8];
#pragma unroll
    for (int j = 0; j < 8; ++j) {
      vb[j] = f2bf(xv[j]);
      vs[j] = f2bf(xv[j] / (1.0f + __expf(-xv[j])));
    }
    ushort_t* row = Apack + ((size_t)b << 11);
    *(short8*)(row + i) = *(short8*)vb;
    *(short8*)(row + IN_F + i) = *(short8*)vs;
  } else if (blk < PREP_A_BLOCKS + PREP_S_BLOCKS) {
    const int idx = (blk - PREP_A_BLOCKS) * 256 + t;
    const int o = idx >> 8;
    const int i0 = (idx & 255) << 2;
    ushort_t vs[4];
#pragma unroll
    for (int j = 0; j < 4; ++j) {
      const float4* p = (const float4*)(Ws + ((((size_t)o << 10) + i0 + j) << 3));
      const float4 a = p[0];
      const float4 b = p[1];
      vs[j] = f2bf(((a.x + a.y) + (a.z + a.w)) + ((b.x + b.y) + (b.z + b.w)));
    }
    *(ushort4*)(Wpack + ((size_t)o << 11) + IN_F + i0) = *(ushort4*)vs;
  } else {
    const int idx = (blk - PREP_A_BLOCKS - PREP_S_BLOCKS) * 256 + t;
    const int o = idx >> 8;
    const int c = (idx & 255) << 2;
    const float4 w = *(const float4*)(Wb + ((size_t)o << 10) + c);
    ushort4 v;
    v.x = f2bf(w.x); v.y = f2bf(w.y); v.z = f2bf(w.z); v.w = f2bf(w.w);
    *(ushort4*)(Wpack + ((size_t)o << 11) + c) = v;
  }
}

// ---------------- GEMM ----------------
// C[M][N] = A[M][K] @ W[N][K]^T. 128x128 tile, BK=32, 256 thr = 4 waves,
// wave tile 64x64 (4x4 frags of 16x16x32). Grid (8,64)=512 blocks, 2/CU.
// LDS per matrix per buffer: [kslot 0..3][physrow 0..127][8 elems=16B] = 8KB,
//   physrow = row ^ (kslot<<2)  (XOR swizzle: conflict-free reads AND writes<=2-way).
// Window: prefetch k+1 -> regs | ds_read frags (buf p) | MFMA x16 |
//         ds_write regs -> buf p^1 (vmcnt wait covered by MFMA) | barrier.
__global__ __launch_bounds__(256) void gemm_packed(
    const ushort_t* __restrict__ A,  // [BATCH][KP]
    const ushort_t* __restrict__ W,  // [OUT_F][KP]
    float* __restrict__ C) {         // [BATCH][OUT_F]
  __shared__ ushort_t As[2 * 4096];  // 2 x 8 KB
  __shared__ ushort_t Bs[2 * 4096];

  const int t = threadIdx.x;
  const int flat = blockIdx.y * 8 + blockIdx.x;
  const int xcd = flat & 7;
  const int local = flat >> 3;           // 0..63
  const int nt = local >> 3;             // N-tile 0..7
  const int mt = xcd * 8 + (local & 7);  // M-tile 0..63 (XCD-local A slab)

  const int lane = t & 63;
  const int wave = t >> 6;
  const int wr = wave >> 1;
  const int wc = wave & 1;

  // staging (coalesced): thread t loads rows r, r+64 at kslot c (16B each)
  const int r = t >> 2;  // 0..63
  const int c = t & 3;   // kslot
  const ushort_t* a_g = A + ((size_t)(mt * 128 + r)) * KP + c * 8;
  const ushort_t* b_g = W + ((size_t)(nt * 128 + r)) * KP + c * 8;
  const size_t rowskip = (size_t)64 * KP;
  // LDS write base: elem = c*1024 + (r ^ (c<<2))*8 ; row+64 -> +512 elems
  const int wbase = c * 1024 + ((r ^ (c << 2)) << 3);

  f32x4 acc[4][4];
#pragma unroll
  for (int mi = 0; mi < 4; ++mi)
#pragma unroll
    for (int ni = 0; ni < 4; ++ni) acc[mi][ni] = (f32x4){0.f, 0.f, 0.f, 0.f};

  // fragment read addressing: kslot = lane>>4, swizzled row
  const int ks = lane >> 4;
  const int ar = (wr * 64 + (lane & 15)) ^ (ks << 2);
  const int br = (wc * 64 + (lane & 15)) ^ (ks << 2);
  const int rbase = ks * 1024;

  // prologue: tile 0 -> regs -> buf 0
  {
    uint4 la0 = *(const uint4*)(a_g);
    uint4 la1 = *(const uint4*)(a_g + rowskip);
    uint4 lb0 = *(const uint4*)(b_g);
    uint4 lb1 = *(const uint4*)(b_g + rowskip);
    *(uint4*)(As + wbase) = la0;
    *(uint4*)(As + wbase + 512) = la1;
    *(uint4*)(Bs + wbase) = lb0;
    *(uint4*)(Bs + wbase + 512) = lb1;
  }
  __syncthreads();

  int poff = 0;
  for (int k0 = 0; k0 < KP; k0 += 32) {
    const bool more = (k0 + 32) < KP;
    // 1) prefetch next tile into registers (non-blocking; consumed after MFMA)
    uint4 na0, na1, nb0, nb1;
    if (more) {
      na0 = *(const uint4*)(a_g + k0 + 32);
      na1 = *(const uint4*)(a_g + k0 + 32 + rowskip);
      nb0 = *(const uint4*)(b_g + k0 + 32);
      nb1 = *(const uint4*)(b_g + k0 + 32 + rowskip);
    }

    // 2) fragment reads from current buffer
    const ushort_t* ab = As + poff + rbase;
    const ushort_t* bb = Bs + poff + rbase;
    short8 af[4], bfr[4];
#pragma unroll
    for (int mi = 0; mi < 4; ++mi)
      af[mi] = *(const short8*)(ab + ((ar + mi * 16) << 3));
#pragma unroll
    for (int ni = 0; ni < 4; ++ni)
      bfr[ni] = *(const short8*)(bb + ((br + ni * 16) << 3));

    // 3) compute (covers prefetch flight time)
#pragma unroll
    for (int mi = 0; mi < 4; ++mi)
#pragma unroll
      for (int ni = 0; ni < 4; ++ni)
        acc[mi][ni] = __builtin_amdgcn_mfma_f32_16x16x32_bf16(af[mi], bfr[ni], acc[mi][ni], 0, 0, 0);

    // 4) stage prefetched tile into the other buffer; ONE barrier, vmcnt
    //    already drained by the ds_write dependency.
    if (more) {
      const int qoff = poff ^ 4096;
      *(uint4*)(As + qoff + wbase) = na0;
      *(uint4*)(As + qoff + wbase + 512) = na1;
      *(uint4*)(Bs + qoff + wbase) = nb0;
      *(uint4*)(Bs + qoff + wbase + 512) = nb1;
      __syncthreads();
    }
    poff ^= 4096;
  }

  const int col0 = nt * 128 + wc * 64 + (lane & 15);
  const int row0 = mt * 128 + wr * 64 + ((lane >> 4) << 2);
#pragma unroll
  for (int mi = 0; mi < 4; ++mi)
#pragma unroll
    for (int ni = 0; ni < 4; ++ni) {
      float* cp = C + (size_t)(row0 + mi * 16) * OUT_F + col0 + ni * 16;
#pragma unroll
      for (int rr = 0; rr < 4; ++rr) cp[(size_t)rr * OUT_F] = acc[mi][ni][rr];
    }
}

extern "C" void kernel_launch(void* const* d_in, const int* in_sizes, int n_in,
                              void* d_out, int out_size, void* d_ws, size_t ws_size,
                              hipStream_t stream) {
  const float* x = (const float*)d_in[0];
  const float* wb = (const float*)d_in[1];
  const float* ws = (const float*)d_in[2];
  float* out = (float*)d_out;

  ushort_t* Apack = (ushort_t*)d_ws;                                    // 33.5 MB
  ushort_t* Wpack = (ushort_t*)((char*)d_ws + (size_t)BATCH * KP * 2);  // +4 MB

  prep_all<<<PREP_BLOCKS, 256, 0, stream>>>(x, wb, ws, Apack, Wpack);
  gemm_packed<<<dim3(OUT_F / 128, BATCH / 128), 256, 0, stream>>>(Apack, Wpack, out);
}